// Round 6
// baseline (126521.277 us; speedup 1.0000x reference)
//
#include <hip/hip_runtime.h>
#include <stdint.h>

// Problem constants
#define NT   8192   // T
#define HID  1024   // H (= I)

// ---------- f16 helpers (packed 2 x f16 in a uint32: lo = elem0, hi = elem1) ----------
typedef _Float16 f16x2 __attribute__((ext_vector_type(2)));
__device__ __forceinline__ uint32_t f16_bits(float a) {
    return (uint32_t)__builtin_bit_cast(uint16_t, (_Float16)a);
}
__device__ __forceinline__ float f16_lo(uint32_t w) {
    return (float)__builtin_bit_cast(_Float16, (uint16_t)(w & 0xffffu));
}
__device__ __forceinline__ float f16_hi(uint32_t w) {
    return (float)__builtin_bit_cast(_Float16, (uint16_t)(w >> 16));
}
__device__ __forceinline__ uint32_t pack_f16(float a, float b) {
    return f16_bits(a) | (f16_bits(b) << 16);
}
__device__ __forceinline__ float dot2(uint32_t a, uint32_t b, float c) {
    return __builtin_amdgcn_fdot2(__builtin_bit_cast(f16x2, a),
                                  __builtin_bit_cast(f16x2, b), c, false);
}
__device__ __forceinline__ float fast_rcp(float x) { return __builtin_amdgcn_rcpf(x); }
__device__ __forceinline__ float fast_sig(float x) { return fast_rcp(1.f + __expf(-x)); }
__device__ __forceinline__ float fast_tanh(float x) {
    return 1.f - 2.f * fast_rcp(1.f + __expf(2.f * x));
}

// ---------- prep: combined bias ----------
__global__ void prep_bias(const float* __restrict__ a, const float* __restrict__ b,
                          float* __restrict__ o) {
    int i = blockIdx.x * 256 + threadIdx.x;
    if (i < 4096) o[i] = a[i] + b[i];
}

// ---------- prep: W_hh -> packed f16, slot layout ----------
// word idx = (((s*8 + v)*16 + rr)*512) + m*64 + L ; rr = gate*4 + jj
// holds cols (2u, 2u+1), u = L + 64m, of row R = gate*1024 + (32s + 4v + jj)
__global__ void prep_whh(const float* __restrict__ Whh, uint32_t* __restrict__ wpk) {
    int idx = blockIdx.x * 256 + threadIdx.x;        // 0 .. 2M-1
    int L  = idx & 63;
    int m  = (idx >> 6) & 7;
    int rr = (idx >> 9) & 15;
    int v  = (idx >> 13) & 7;
    int s  = idx >> 16;
    int gate = rr >> 2, jj = rr & 3;
    int R = gate * 1024 + s * 32 + v * 4 + jj;
    int u = L + 64 * m;
    const float* rp = Whh + (size_t)R * 1024 + 2 * u;
    wpk[idx] = pack_f16(rp[0], rp[1]);
}

// ---------- fp32 tiled GEMM: out[M][N] = A[M][K] @ B[N][K]^T + bias[N] ----------
template <bool PACK_OUT>
__launch_bounds__(256)
__global__ void gemm_bt(const float* __restrict__ A, const float* __restrict__ B,
                        const float* __restrict__ bias, void* __restrict__ outp,
                        int N, int K) {
    __shared__ float As[16 * 132];
    __shared__ float Bs[16 * 132];
    const int tid = threadIdx.x;
    const int bm = blockIdx.x, bn = blockIdx.y;
    const int tx = tid & 15, ty = tid >> 4;
    const int r = tid >> 2, cf = tid & 3;

    float acc[8][8];
#pragma unroll
    for (int i = 0; i < 8; ++i)
#pragma unroll
        for (int j = 0; j < 8; ++j) acc[i][j] = 0.f;

    const float* Ap = A + (size_t)(bm * 128 + r) * K + cf * 4;
    const float* Bp = B + (size_t)(bn * 128 + r) * K + cf * 4;

    for (int k0 = 0; k0 < K; k0 += 16) {
        float4 a0 = *(const float4*)(Ap + k0);
        float4 a1 = *(const float4*)(Ap + (size_t)64 * K + k0);
        float4 b0 = *(const float4*)(Bp + k0);
        float4 b1 = *(const float4*)(Bp + (size_t)64 * K + k0);
        __syncthreads();
#pragma unroll
        for (int e = 0; e < 4; ++e) {
            As[(cf * 4 + e) * 132 + r]      = ((const float*)&a0)[e];
            As[(cf * 4 + e) * 132 + r + 64] = ((const float*)&a1)[e];
            Bs[(cf * 4 + e) * 132 + r]      = ((const float*)&b0)[e];
            Bs[(cf * 4 + e) * 132 + r + 64] = ((const float*)&b1)[e];
        }
        __syncthreads();
#pragma unroll
        for (int k = 0; k < 16; ++k) {
            const float4 av0 = *(const float4*)&As[k * 132 + ty * 8];
            const float4 av1 = *(const float4*)&As[k * 132 + ty * 8 + 4];
            const float4 bv0 = *(const float4*)&Bs[k * 132 + tx * 4];
            const float4 bv1 = *(const float4*)&Bs[k * 132 + tx * 4 + 64];
            const float a[8] = {av0.x, av0.y, av0.z, av0.w, av1.x, av1.y, av1.z, av1.w};
            const float b[8] = {bv0.x, bv0.y, bv0.z, bv0.w, bv1.x, bv1.y, bv1.z, bv1.w};
#pragma unroll
            for (int i = 0; i < 8; ++i)
#pragma unroll
                for (int j = 0; j < 8; ++j) acc[i][j] = fmaf(a[i], b[j], acc[i][j]);
        }
    }

    const int mb = bm * 128 + ty * 8;
    const int n0 = bn * 128 + tx * 4, n1 = n0 + 64;
    float bb[8];
#pragma unroll
    for (int j = 0; j < 4; ++j) { bb[j] = bias[n0 + j]; bb[4 + j] = bias[n1 + j]; }

    if (PACK_OUT) {
        uint32_t* o = (uint32_t*)outp;
        const int halfN = N >> 1;
#pragma unroll
        for (int i = 0; i < 8; ++i) {
            uint2 w0, w1;
            w0.x = pack_f16(acc[i][0] + bb[0], acc[i][1] + bb[1]);
            w0.y = pack_f16(acc[i][2] + bb[2], acc[i][3] + bb[3]);
            w1.x = pack_f16(acc[i][4] + bb[4], acc[i][5] + bb[5]);
            w1.y = pack_f16(acc[i][6] + bb[6], acc[i][7] + bb[7]);
            *(uint2*)(o + (size_t)(mb + i) * halfN + (n0 >> 1)) = w0;
            *(uint2*)(o + (size_t)(mb + i) * halfN + (n1 >> 1)) = w1;
        }
    } else {
        float* o = (float*)outp;
#pragma unroll
        for (int i = 0; i < 8; ++i) {
            float4 v0, v1;
            v0.x = acc[i][0] + bb[0]; v0.y = acc[i][1] + bb[1];
            v0.z = acc[i][2] + bb[2]; v0.w = acc[i][3] + bb[3];
            v1.x = acc[i][4] + bb[4]; v1.y = acc[i][5] + bb[5];
            v1.z = acc[i][6] + bb[6]; v1.w = acc[i][7] + bb[7];
            *(float4*)(o + (size_t)(mb + i) * N + n0) = v0;
            *(float4*)(o + (size_t)(mb + i) * N + n1) = v1;
        }
    }
}

// ---------- persistent LSTM recurrence, single-XCD, L2-coherent sc0 exchange ----------
// 256 WGs x 512 thr, 96KB LDS forcer => 1 WG/CU => exactly 32 WGs per XCD. The 32 WGs
// on the elected XCD claim slots 0..31; all others exit. Slot s owns units 32s..32s+31;
// wave v owns units 32s+4v..+3 (rows rr = gate*4+jj). Weights in VGPRs (128/lane).
// h word j = (tag<<16)|f16(h_j); u64 k = words (2k,2k+1); double-buffered by parity.
// Exchange via sc0 (L1-bypass, XCD-L2-served) loads/stores: ~200cy instead of ~900ns MALL.
__launch_bounds__(512, 2)
__global__ void lstm_rec(const uint32_t* __restrict__ wpk, const uint32_t* __restrict__ pxp,
                         uint32_t* htag, uint32_t* claim, float* __restrict__ lstm_out) {
    extern __shared__ uint32_t lds_forcer[];
    __shared__ int sSlot;
    const int tid = threadIdx.x;

    if (tid == 0) {
        uint32_t xcc = 0;
        asm volatile("s_getreg_b32 %0, hwreg(HW_REG_XCC_ID)" : "=s"(xcc));
        atomicCAS(claim, 0u, xcc + 1u);            // elect: first arriver's XCD
        uint32_t chosen;
        do {
            chosen = __hip_atomic_load(claim, __ATOMIC_RELAXED, __HIP_MEMORY_SCOPE_AGENT);
        } while (chosen == 0u);
        int slot = -1;
        if (chosen == xcc + 1u) slot = (int)atomicAdd(claim + 1, 1u);
        sSlot = (slot < 32) ? slot : -1;
    }
    __syncthreads();
    const int s = sSlot;
    if (s < 0) return;

    const int v = tid >> 6, L = tid & 63;

    // stage this wave's weight slice into VGPRs (static indexing -> registers)
    uint32_t wreg[16][8];
    {
        const uint32_t* wb = wpk + (size_t)((s * 8 + v) * 16) * 512 + L;
#pragma unroll
        for (int rr = 0; rr < 16; ++rr)
#pragma unroll
            for (int m = 0; m < 8; ++m)
                wreg[rr][m] = wb[rr * 512 + m * 64];
    }

    float c0 = 0.f;                                  // cell state, lanes 0..3
    const uint64_t* buf0 = (const uint64_t*)htag;    // 512 u64 (H[even])
    const uint64_t* buf1 = buf0 + 512;               //          (H[odd])
    const uint32_t voff_h = (uint32_t)(L * 8);
    const int unitb = s * 32 + v * 4;
    const uint32_t vA_base = (uint32_t)((16 * s + 2 * v + ((L & 3) >> 1)) * 4);
    const uint32_t pxsel = L & 1;
    const uint32_t pub_off = (uint32_t)((16 * s + 2 * v) * 8);
    int tries = 0;                                   // cumulative tripwire budget

    for (int t = 0; t < NT; ++t) {
        const uint32_t tg = (uint32_t)t;
        const uint64_t* srcb = (t & 1) ? buf1 : buf0;
        uint64_t* dstb = (uint64_t*)((t & 1) ? buf0 : buf1);
        uint32_t vA = vA_base + (uint32_t)t * 8192u;
        uint32_t vB = vA + 4096u;

        uint64_t h0, h1, h2, h3, h4, h5, h6, h7;
        uint32_t p0, p1, p2, p3;
        // 8 h-line loads (sc0, L2-coherent) + 4 px loads; wait h only (px stays in flight)
        asm volatile(
            "global_load_dwordx2 %0, %12, %13 sc0\n\t"
            "global_load_dwordx2 %1, %12, %13 offset:512 sc0\n\t"
            "global_load_dwordx2 %2, %12, %13 offset:1024 sc0\n\t"
            "global_load_dwordx2 %3, %12, %13 offset:1536 sc0\n\t"
            "global_load_dwordx2 %4, %12, %13 offset:2048 sc0\n\t"
            "global_load_dwordx2 %5, %12, %13 offset:2560 sc0\n\t"
            "global_load_dwordx2 %6, %12, %13 offset:3072 sc0\n\t"
            "global_load_dwordx2 %7, %12, %13 offset:3584 sc0\n\t"
            "global_load_dword %8, %14, %16\n\t"
            "global_load_dword %9, %14, %16 offset:2048\n\t"
            "global_load_dword %10, %15, %16\n\t"
            "global_load_dword %11, %15, %16 offset:2048\n\t"
            "s_waitcnt vmcnt(4)"
            : "=&v"(h0), "=&v"(h1), "=&v"(h2), "=&v"(h3),
              "=&v"(h4), "=&v"(h5), "=&v"(h6), "=&v"(h7),
              "=&v"(p0), "=&v"(p1), "=&v"(p2), "=&v"(p3)
            : "v"(voff_h), "s"(srcb), "v"(vA), "v"(vB), "s"(pxp)
            : "memory");

        // wave-uniform poll: reload all 8 until every lane sees fresh tags
        for (;;) {
            int ok = ((((uint32_t)h0 >> 16) == tg) & (((uint32_t)(h0 >> 48)) == tg)) &
                     ((((uint32_t)h1 >> 16) == tg) & (((uint32_t)(h1 >> 48)) == tg)) &
                     ((((uint32_t)h2 >> 16) == tg) & (((uint32_t)(h2 >> 48)) == tg)) &
                     ((((uint32_t)h3 >> 16) == tg) & (((uint32_t)(h3 >> 48)) == tg)) &
                     ((((uint32_t)h4 >> 16) == tg) & (((uint32_t)(h4 >> 48)) == tg)) &
                     ((((uint32_t)h5 >> 16) == tg) & (((uint32_t)(h5 >> 48)) == tg)) &
                     ((((uint32_t)h6 >> 16) == tg) & (((uint32_t)(h6 >> 48)) == tg)) &
                     ((((uint32_t)h7 >> 16) == tg) & (((uint32_t)(h7 >> 48)) == tg));
            if (__all(ok) || ++tries > (1 << 18)) break;   // cumulative tripwire
            asm volatile(
                "global_load_dwordx2 %0, %8, %9 sc0\n\t"
                "global_load_dwordx2 %1, %8, %9 offset:512 sc0\n\t"
                "global_load_dwordx2 %2, %8, %9 offset:1024 sc0\n\t"
                "global_load_dwordx2 %3, %8, %9 offset:1536 sc0\n\t"
                "global_load_dwordx2 %4, %8, %9 offset:2048 sc0\n\t"
                "global_load_dwordx2 %5, %8, %9 offset:2560 sc0\n\t"
                "global_load_dwordx2 %6, %8, %9 offset:3072 sc0\n\t"
                "global_load_dwordx2 %7, %8, %9 offset:3584 sc0\n\t"
                "s_waitcnt vmcnt(0)"
                : "=&v"(h0), "=&v"(h1), "=&v"(h2), "=&v"(h3),
                  "=&v"(h4), "=&v"(h5), "=&v"(h6), "=&v"(h7)
                : "v"(voff_h), "s"(srcb)
                : "memory");
        }

        // repack: hk[m] = f16 pair (h[2(L+64m)], h[2(L+64m)+1])
        uint32_t hk[8];
        hk[0] = ((uint32_t)h0 & 0xffffu) | ((uint32_t)(h0 >> 32) << 16);
        hk[1] = ((uint32_t)h1 & 0xffffu) | ((uint32_t)(h1 >> 32) << 16);
        hk[2] = ((uint32_t)h2 & 0xffffu) | ((uint32_t)(h2 >> 32) << 16);
        hk[3] = ((uint32_t)h3 & 0xffffu) | ((uint32_t)(h3 >> 32) << 16);
        hk[4] = ((uint32_t)h4 & 0xffffu) | ((uint32_t)(h4 >> 32) << 16);
        hk[5] = ((uint32_t)h5 & 0xffffu) | ((uint32_t)(h5 >> 32) << 16);
        hk[6] = ((uint32_t)h6 & 0xffffu) | ((uint32_t)(h6 >> 32) << 16);
        hk[7] = ((uint32_t)h7 & 0xffffu) | ((uint32_t)(h7 >> 32) << 16);

        // 16 row-dots via v_dot2_f32_f16 (2 MACs/inst, f32 accum)
        float acc[16];
#pragma unroll
        for (int rr = 0; rr < 16; ++rr) {
            float a = 0.f;
#pragma unroll
            for (int m = 0; m < 8; ++m) a = dot2(wreg[rr][m], hk[m], a);
            acc[rr] = a;
        }

        // folded butterfly reduction (verified in rounds 3/4)
#pragma unroll
        for (int bit = 8; bit >= 1; bit >>= 1) {
#pragma unroll
            for (int i = 0; i < bit; ++i) {
                float v0 = acc[i], v1 = acc[i + bit];
                float send = (L & bit) ? v0 : v1;
                float recv = __shfl_xor(send, bit, 64);
                acc[i] = ((L & bit) ? v1 : v0) + recv;
            }
        }
        float tot = acc[0];
        tot += __shfl_xor(tot, 16, 64);
        tot += __shfl_xor(tot, 32, 64);
        float g1 = __shfl(tot, (L & 3) + 4, 64);
        float g2 = __shfl(tot, (L & 3) + 8, 64);
        float g3 = __shfl(tot, (L & 3) + 12, 64);

        // px now safe to consume
        asm volatile("s_waitcnt vmcnt(0)" ::: "memory");
        __builtin_amdgcn_sched_barrier(0);
        float px0 = pxsel ? f16_hi(p0) : f16_lo(p0);
        float px1 = pxsel ? f16_hi(p1) : f16_lo(p1);
        float px2 = pxsel ? f16_hi(p2) : f16_lo(p2);
        float px3 = pxsel ? f16_hi(p3) : f16_lo(p3);

        float gi = tot + px0;
        float gf = g1 + px1;
        float gg = g2 + px2;
        float go = g3 + px3;
        float iv = fast_sig(gi);
        float fv = fast_sig(gf);
        float gv = fast_tanh(gg);
        float ov = fast_sig(go);
        c0 = fv * c0 + iv * gv;                    // meaningful on lanes 0..3 only
        float h = ov * fast_tanh(c0);

        uint32_t word = f16_bits(h) | ((uint32_t)(t + 1) << 16);
        uint32_t wd1 = (uint32_t)__shfl((int)word, 1, 64);
        uint32_t wd2 = (uint32_t)__shfl((int)word, 2, 64);
        uint32_t wd3 = (uint32_t)__shfl((int)word, 3, 64);
        float hs1 = __shfl(h, 1, 64);
        float hs2 = __shfl(h, 2, 64);
        float hs3 = __shfl(h, 3, 64);
        if (L == 0) {
            uint64_t qa = (uint64_t)word | ((uint64_t)wd1 << 32);
            uint64_t qb = (uint64_t)wd2 | ((uint64_t)wd3 << 32);
            asm volatile(
                "global_store_dwordx2 %0, %1, %3 sc0\n\t"
                "global_store_dwordx2 %0, %2, %3 offset:8 sc0"
                :: "v"(pub_off), "v"(qa), "v"(qb), "s"(dstb)
                : "memory");
            *(float4*)(lstm_out + (size_t)t * 1024 + unitb) = make_float4(h, hs1, hs2, hs3);
        }
    }
    (void)lds_forcer;
}

// ---------- log-softmax over axis 0 (columns of [8192][512]) ----------
__global__ void sm_partial(const float* __restrict__ logits, float* __restrict__ pM,
                           float* __restrict__ pS) {
    const int cb = blockIdx.x, rb = blockIdx.y, tid = threadIdx.x;
    const int c = cb * 64 + (tid & 63);
    const int r0 = rb * 256 + (tid >> 6) * 64;
    const float* p = logits + (size_t)r0 * 512 + c;
    float m = -1e30f;
    for (int k = 0; k < 64; ++k) m = fmaxf(m, p[(size_t)k * 512]);
    float s = 0.f;
    for (int k = 0; k < 64; ++k) s += __expf(p[(size_t)k * 512] - m);
    __shared__ float sM[4][64], sS[4][64];
    sM[tid >> 6][tid & 63] = m;
    sS[tid >> 6][tid & 63] = s;
    __syncthreads();
    if (tid < 64) {
        float M = sM[0][tid];
        for (int i = 1; i < 4; ++i) M = fmaxf(M, sM[i][tid]);
        float S = 0.f;
        for (int i = 0; i < 4; ++i) S += sS[i][tid] * __expf(sM[i][tid] - M);
        pM[rb * 512 + cb * 64 + tid] = M;
        pS[rb * 512 + cb * 64 + tid] = S;
    }
}

__global__ void sm_combine(const float* __restrict__ pM, const float* __restrict__ pS,
                           float* __restrict__ cc) {
    const int c = threadIdx.x;   // 512 threads
    float M = -1e30f;
    for (int i = 0; i < 32; ++i) M = fmaxf(M, pM[i * 512 + c]);
    float S = 0.f;
    for (int i = 0; i < 32; ++i) S += pS[i * 512 + c] * __expf(pM[i * 512 + c] - M);
    cc[c] = M + logf(S);
}

__global__ void sm_apply(float* __restrict__ out, const float* __restrict__ cc) {
    const int idx = blockIdx.x * 256 + threadIdx.x;    // float4 index, exactly 1M
    float4 v = ((const float4*)out)[idx];
    float4 b = ((const float4*)cc)[idx & 127];
    v.x -= b.x; v.y -= b.y; v.z -= b.z; v.w -= b.w;
    ((float4*)out)[idx] = v;
}

// ---------- launch ----------
extern "C" void kernel_launch(void* const* d_in, const int* in_sizes, int n_in,
                              void* d_out, int out_size, void* d_ws, size_t ws_size,
                              hipStream_t stream) {
    (void)in_sizes; (void)n_in; (void)out_size; (void)ws_size;
    const float* x    = (const float*)d_in[0];
    const float* Wih  = (const float*)d_in[1];
    const float* Whh  = (const float*)d_in[2];
    const float* bih  = (const float*)d_in[3];
    const float* bhh  = (const float*)d_in[4];
    const float* Wout = (const float*)d_in[5];
    const float* bout = (const float*)d_in[6];
    float* out = (float*)d_out;

    char* ws = (char*)d_ws;
    uint32_t* pxp   = (uint32_t*)(ws + 0ull);            // 8192*2048 words   (67,108,864 B)
    uint32_t* wpk   = (uint32_t*)(ws + 67108864ull);     // 2M words          ( 8,388,608 B)
    float* lstm_out = (float*)   (ws + 75497472ull);     // 8192*1024 f32     (33,554,432 B)
    float* biasc    = (float*)   (ws + 109051904ull);    // 4096 f32 (16 KB)
    uint32_t* htag  = (uint32_t*)(ws + 109068288ull);    // 2*512 u64 (8 KB)
    uint32_t* claim = (uint32_t*)(ws + 109076480ull);    // 2 u32 (+pad 256 B)
    float* pM       = (float*)   (ws + 109076736ull);    // 32*512 f32 (64 KB)
    float* pS       = (float*)   (ws + 109142272ull);    // 32*512 f32 (64 KB)
    float* cc       = (float*)   (ws + 109207808ull);    // 512 f32

    // deterministic per-call state: H[0] = 0 with tag 0 (both parity buffers), claim clear
    hipMemsetAsync(htag, 0, 8192, stream);
    hipMemsetAsync(claim, 0, 256, stream);

    prep_whh<<<8192, 256, 0, stream>>>(Whh, wpk);
    prep_bias<<<16, 256, 0, stream>>>(bih, bhh, biasc);

    // px = x @ W_ih^T + (b_ih + b_hh), stored packed f16
    gemm_bt<true><<<dim3(64, 32), 256, 0, stream>>>(x, Wih, biasc, (void*)pxp, 4096, 1024);

    hipFuncSetAttribute(reinterpret_cast<const void*>(&lstm_rec),
                        hipFuncAttributeMaxDynamicSharedMemorySize, 98304);
    lstm_rec<<<256, 512, 98304, stream>>>(wpk, pxp, htag, claim, lstm_out);

    // logits = lstm_out @ W_out^T + b_out  -> d_out
    gemm_bt<false><<<dim3(64, 4), 256, 0, stream>>>(lstm_out, Wout, bout, (void*)out, 512, 1024);

    // log-softmax over sequence axis (columns)
    sm_partial<<<dim3(8, 32), 256, 0, stream>>>(out, pM, pS);
    sm_combine<<<1, 512, 0, stream>>>(pM, pS, cc);
    sm_apply<<<4096, 256, 0, stream>>>(out, cc);
}

// Round 7
// 25355.751 us; speedup vs baseline: 4.9898x; 4.9898x over previous
//
#include <hip/hip_runtime.h>
#include <stdint.h>

// Problem constants
#define NT   8192   // T
#define HID  1024   // H (= I)
#define NWG  128    // persistent workgroups in recurrence

// ---------- bf16 helpers (packed 2 x bf16 in a uint32: lo = elem0, hi = elem1) ----------
__device__ __forceinline__ float lo_f(uint32_t w) { return __uint_as_float(w << 16); }
__device__ __forceinline__ float hi_f(uint32_t w) { return __uint_as_float(w & 0xffff0000u); }
__device__ __forceinline__ uint32_t bf16_bits(float a) {
    uint32_t ua = __float_as_uint(a);
    ua = (ua + 0x7fffu + ((ua >> 16) & 1u)) >> 16;   // RNE
    return ua & 0xffffu;
}
__device__ __forceinline__ uint32_t pack_bf16(float a, float b) {
    return bf16_bits(a) | (bf16_bits(b) << 16);
}
__device__ __forceinline__ float fast_rcp(float x) { return __builtin_amdgcn_rcpf(x); }
__device__ __forceinline__ float fast_sig(float x) { return fast_rcp(1.f + __expf(-x)); }
__device__ __forceinline__ float fast_tanh(float x) {
    return 1.f - 2.f * fast_rcp(1.f + __expf(2.f * x));
}

// ---------- prep: combined bias ----------
__global__ void prep_bias(const float* __restrict__ a, const float* __restrict__ b,
                          float* __restrict__ o) {
    int i = blockIdx.x * 256 + threadIdx.x;
    if (i < 4096) o[i] = a[i] + b[i];
}

// ---------- prep: W_hh -> packed bf16, per-WG layout ----------
// Layout: wpk[w][lr][u], lr = wave*8 + gate*2 + jj  <->  row R = gate*1024 + w*8 + 2*wave + jj
// word u packs cols (2u, 2u+1)
__global__ void prep_whh(const float* __restrict__ Whh, uint32_t* __restrict__ wpk) {
    int idx = blockIdx.x * 256 + threadIdx.x;        // 0 .. 128*32*512-1
    int u    = idx & 511;
    int lr   = (idx >> 9) & 31;
    int w    = idx >> 14;
    int v    = lr >> 3;
    int gate = (lr >> 1) & 3;
    int jj   = lr & 1;
    int R = gate * 1024 + w * 8 + 2 * v + jj;
    const float* rp = Whh + (size_t)R * 1024 + 2 * u;
    wpk[idx] = pack_bf16(rp[0], rp[1]);
}

// ---------- fp32 tiled GEMM: out[M][N] = A[M][K] @ B[N][K]^T + bias[N] ----------
// 128x128 tile, BK=16, 256 threads, 8x8 microtile. PACK_OUT: write packed bf16 pairs.
template <bool PACK_OUT>
__launch_bounds__(256)
__global__ void gemm_bt(const float* __restrict__ A, const float* __restrict__ B,
                        const float* __restrict__ bias, void* __restrict__ outp,
                        int N, int K) {
    __shared__ float As[16 * 132];
    __shared__ float Bs[16 * 132];
    const int tid = threadIdx.x;
    const int bm = blockIdx.x, bn = blockIdx.y;
    const int tx = tid & 15, ty = tid >> 4;
    const int r = tid >> 2, cf = tid & 3;

    float acc[8][8];
#pragma unroll
    for (int i = 0; i < 8; ++i)
#pragma unroll
        for (int j = 0; j < 8; ++j) acc[i][j] = 0.f;

    const float* Ap = A + (size_t)(bm * 128 + r) * K + cf * 4;
    const float* Bp = B + (size_t)(bn * 128 + r) * K + cf * 4;

    for (int k0 = 0; k0 < K; k0 += 16) {
        float4 a0 = *(const float4*)(Ap + k0);
        float4 a1 = *(const float4*)(Ap + (size_t)64 * K + k0);
        float4 b0 = *(const float4*)(Bp + k0);
        float4 b1 = *(const float4*)(Bp + (size_t)64 * K + k0);
        __syncthreads();   // protect previous iteration's LDS reads
#pragma unroll
        for (int e = 0; e < 4; ++e) {
            As[(cf * 4 + e) * 132 + r]      = ((const float*)&a0)[e];
            As[(cf * 4 + e) * 132 + r + 64] = ((const float*)&a1)[e];
            Bs[(cf * 4 + e) * 132 + r]      = ((const float*)&b0)[e];
            Bs[(cf * 4 + e) * 132 + r + 64] = ((const float*)&b1)[e];
        }
        __syncthreads();
#pragma unroll
        for (int k = 0; k < 16; ++k) {
            const float4 av0 = *(const float4*)&As[k * 132 + ty * 8];
            const float4 av1 = *(const float4*)&As[k * 132 + ty * 8 + 4];
            const float4 bv0 = *(const float4*)&Bs[k * 132 + tx * 4];
            const float4 bv1 = *(const float4*)&Bs[k * 132 + tx * 4 + 64];
            const float a[8] = {av0.x, av0.y, av0.z, av0.w, av1.x, av1.y, av1.z, av1.w};
            const float b[8] = {bv0.x, bv0.y, bv0.z, bv0.w, bv1.x, bv1.y, bv1.z, bv1.w};
#pragma unroll
            for (int i = 0; i < 8; ++i)
#pragma unroll
                for (int j = 0; j < 8; ++j) acc[i][j] = fmaf(a[i], b[j], acc[i][j]);
        }
    }

    const int mb = bm * 128 + ty * 8;
    const int n0 = bn * 128 + tx * 4, n1 = n0 + 64;
    float bb[8];
#pragma unroll
    for (int j = 0; j < 4; ++j) { bb[j] = bias[n0 + j]; bb[4 + j] = bias[n1 + j]; }

    if (PACK_OUT) {
        uint32_t* o = (uint32_t*)outp;
        const int halfN = N >> 1;
#pragma unroll
        for (int i = 0; i < 8; ++i) {
            uint2 w0, w1;
            w0.x = pack_bf16(acc[i][0] + bb[0], acc[i][1] + bb[1]);
            w0.y = pack_bf16(acc[i][2] + bb[2], acc[i][3] + bb[3]);
            w1.x = pack_bf16(acc[i][4] + bb[4], acc[i][5] + bb[5]);
            w1.y = pack_bf16(acc[i][6] + bb[6], acc[i][7] + bb[7]);
            *(uint2*)(o + (size_t)(mb + i) * halfN + (n0 >> 1)) = w0;
            *(uint2*)(o + (size_t)(mb + i) * halfN + (n1 >> 1)) = w1;
        }
    } else {
        float* o = (float*)outp;
#pragma unroll
        for (int i = 0; i < 8; ++i) {
            float4 v0, v1;
            v0.x = acc[i][0] + bb[0]; v0.y = acc[i][1] + bb[1];
            v0.z = acc[i][2] + bb[2]; v0.w = acc[i][3] + bb[3];
            v1.x = acc[i][4] + bb[4]; v1.y = acc[i][5] + bb[5];
            v1.z = acc[i][6] + bb[6]; v1.w = acc[i][7] + bb[7];
            *(float4*)(o + (size_t)(mb + i) * N + n0) = v0;
            *(float4*)(o + (size_t)(mb + i) * N + n1) = v1;
        }
    }
}

// ---------- persistent LSTM recurrence, barrier-free tagged dataflow ----------
// h word j = (tag<<16) | bf16(h_j). H[s] lives in buf[s&1], tagged s. H[0]=tag 0=memset 0.
// Writer of H[s] observed all tags s-1 => every wave finished reading H[s-2] => safe to
// overwrite buf[s&1] (which held H[s-2]). No barriers, no fences, no intra-WG sync in loop.
// 128 WGs x 256 threads; WG w owns units 8w..8w+7; wave v owns units 8w+2v, 8w+2v+1.
// Weights live in VGPRs (64 u32/lane, statically indexed) -- no LDS in the loop.
__launch_bounds__(256)
__global__ void lstm_rec(const uint32_t* __restrict__ wpk, const uint32_t* __restrict__ pxp,
                         uint32_t* htag, float* __restrict__ lstm_out) {
    const int tid = threadIdx.x, w = blockIdx.x;
    const int wave = tid >> 6, L = tid & 63;

    // stage this wave's weight slice into VGPRs (coalesced; static indexing -> registers)
    uint32_t wreg[8][8];
    {
        const uint32_t* wb = wpk + (size_t)w * 16384 + (size_t)(wave * 8) * 512 + L;
#pragma unroll
        for (int rr = 0; rr < 8; ++rr)
#pragma unroll
            for (int m = 0; m < 8; ++m)
                wreg[rr][m] = wb[rr * 512 + m * 64];
    }

    float c0 = 0.f;                    // cell state, live only in lanes 0,1 of each wave
    uint64_t* buf0 = (uint64_t*)htag;          // 512 u64 = words 0..1023   (H[even])
    uint64_t* buf1 = (uint64_t*)(htag + 1024); //                           (H[odd])

    for (int t = 0; t < NT; ++t) {
        const uint32_t tg = (uint32_t)t;            // tag of H[t]
        uint64_t* srcb = (t & 1) ? buf1 : buf0;     // H[t]
        uint32_t* dstb = (uint32_t*)((t & 1) ? buf0 : buf1);  // H[t+1]

        // px for my gates — plain cached loads, issued before the poll so the
        // latency hides under it
        float pxv[4] = {0.f, 0.f, 0.f, 0.f};
        if (L < 2) {
#pragma unroll
            for (int g = 0; g < 4; ++g) {
                int R = g * 1024 + w * 8 + 2 * wave + L;
                uint32_t pw = pxp[(size_t)t * 2048 + (R >> 1)];
                pxv[g] = (R & 1) ? hi_f(pw) : lo_f(pw);
            }
        }

        // poll all 1024 tagged h words (each lane: 8 x u64 = pairs (2(L+64m), +1))
        uint64_t hp[8];
        int tries = 0;
        for (;;) {
            int ok = 1;
#pragma unroll
            for (int m = 0; m < 8; ++m)
                hp[m] = __hip_atomic_load(srcb + (L + 64 * m),
                                          __ATOMIC_RELAXED, __HIP_MEMORY_SCOPE_AGENT);
#pragma unroll
            for (int m = 0; m < 8; ++m) {
                uint32_t lo = (uint32_t)hp[m], hi = (uint32_t)(hp[m] >> 32);
                ok &= ((lo >> 16) == tg) & ((hi >> 16) == tg);
            }
            if (__all(ok)) break;
            if (++tries > (1 << 15)) break;   // tripwire: hang -> visible absmax failure
        }

        float hf[16];
#pragma unroll
        for (int m = 0; m < 8; ++m) {
            hf[2 * m]     = __uint_as_float(((uint32_t)hp[m]) << 16);
            hf[2 * m + 1] = __uint_as_float(((uint32_t)(hp[m] >> 32)) << 16);
        }

        // 8 row-dots: row rr = gate*2 + jj, lane handles cols 2(L+64m), 2(L+64m)+1
        float acc[8];
#pragma unroll
        for (int rr = 0; rr < 8; ++rr) {
            float a = 0.f;
#pragma unroll
            for (int m = 0; m < 8; ++m) {
                uint32_t wv = wreg[rr][m];
                a = fmaf(lo_f(wv), hf[2 * m], a);
                a = fmaf(hi_f(wv), hf[2 * m + 1], a);
            }
            acc[rr] = a;
        }
        // wave-wide butterfly reduction
#pragma unroll
        for (int rr = 0; rr < 8; ++rr) {
#pragma unroll
            for (int off = 32; off; off >>= 1) acc[rr] += __shfl_xor(acc[rr], off, 64);
        }

        // elementwise gate update: lanes 0,1 of each wave (jj = L)
        if (L < 2) {
            float gi = acc[0 + L] + pxv[0];
            float gf = acc[2 + L] + pxv[1];
            float gg = acc[4 + L] + pxv[2];
            float go = acc[6 + L] + pxv[3];
            float iv = fast_sig(gi);
            float fv = fast_sig(gf);
            float gv = fast_tanh(gg);
            float ov = fast_sig(go);
            c0 = fv * c0 + iv * gv;
            float h = ov * fast_tanh(c0);
            int j = w * 8 + 2 * wave + L;
            // publish tagged h FIRST (critical path), then the log
            uint32_t word = bf16_bits(h) | ((uint32_t)(t + 1) << 16);
            __hip_atomic_store(dstb + j, word, __ATOMIC_RELAXED, __HIP_MEMORY_SCOPE_AGENT);
            lstm_out[(size_t)t * 1024 + j] = h;
        }
    }
}

// ---------- log-softmax over axis 0 (columns of [8192][512]) ----------
__global__ void sm_partial(const float* __restrict__ logits, float* __restrict__ pM,
                           float* __restrict__ pS) {
    const int cb = blockIdx.x, rb = blockIdx.y, tid = threadIdx.x;
    const int c = cb * 64 + (tid & 63);
    const int r0 = rb * 256 + (tid >> 6) * 64;
    const float* p = logits + (size_t)r0 * 512 + c;
    float m = -1e30f;
    for (int k = 0; k < 64; ++k) m = fmaxf(m, p[(size_t)k * 512]);
    float s = 0.f;
    for (int k = 0; k < 64; ++k) s += __expf(p[(size_t)k * 512] - m);
    __shared__ float sM[4][64], sS[4][64];
    sM[tid >> 6][tid & 63] = m;
    sS[tid >> 6][tid & 63] = s;
    __syncthreads();
    if (tid < 64) {
        float M = sM[0][tid];
        for (int i = 1; i < 4; ++i) M = fmaxf(M, sM[i][tid]);
        float S = 0.f;
        for (int i = 0; i < 4; ++i) S += sS[i][tid] * __expf(sM[i][tid] - M);
        pM[rb * 512 + cb * 64 + tid] = M;
        pS[rb * 512 + cb * 64 + tid] = S;
    }
}

__global__ void sm_combine(const float* __restrict__ pM, const float* __restrict__ pS,
                           float* __restrict__ cc) {
    const int c = threadIdx.x;   // 512 threads
    float M = -1e30f;
    for (int i = 0; i < 32; ++i) M = fmaxf(M, pM[i * 512 + c]);
    float S = 0.f;
    for (int i = 0; i < 32; ++i) S += pS[i * 512 + c] * __expf(pM[i * 512 + c] - M);
    cc[c] = M + logf(S);
}

__global__ void sm_apply(float* __restrict__ out, const float* __restrict__ cc) {
    const int idx = blockIdx.x * 256 + threadIdx.x;    // float4 index, exactly 1M
    float4 v = ((const float4*)out)[idx];
    float4 b = ((const float4*)cc)[idx & 127];
    v.x -= b.x; v.y -= b.y; v.z -= b.z; v.w -= b.w;
    ((float4*)out)[idx] = v;
}

// ---------- launch ----------
extern "C" void kernel_launch(void* const* d_in, const int* in_sizes, int n_in,
                              void* d_out, int out_size, void* d_ws, size_t ws_size,
                              hipStream_t stream) {
    (void)in_sizes; (void)n_in; (void)out_size; (void)ws_size;
    const float* x    = (const float*)d_in[0];
    const float* Wih  = (const float*)d_in[1];
    const float* Whh  = (const float*)d_in[2];
    const float* bih  = (const float*)d_in[3];
    const float* bhh  = (const float*)d_in[4];
    const float* Wout = (const float*)d_in[5];
    const float* bout = (const float*)d_in[6];
    float* out = (float*)d_out;

    char* ws = (char*)d_ws;
    uint32_t* pxp   = (uint32_t*)(ws + 0ull);            // 8192*2048 words   (67,108,864 B)
    uint32_t* wpk   = (uint32_t*)(ws + 67108864ull);     // 128*32*512 words  ( 8,388,608 B)
    float* lstm_out = (float*)   (ws + 75497472ull);     // 8192*1024 f32     (33,554,432 B)
    float* biasc    = (float*)   (ws + 109051904ull);    // 4096 f32 (16 KB)
    uint32_t* htag  = (uint32_t*)(ws + 109068288ull);    // 2*1024 words (8 KB)
    float* pM       = (float*)   (ws + 109076480ull);    // 32*512 f32 (64 KB)
    float* pS       = (float*)   (ws + 109142016ull);    // 32*512 f32 (64 KB)
    float* cc       = (float*)   (ws + 109207552ull);    // 512 f32

    // deterministic per-call state: H[0] = 0 with tag 0
    hipMemsetAsync(htag, 0, 8192, stream);

    prep_whh<<<8192, 256, 0, stream>>>(Whh, wpk);
    prep_bias<<<16, 256, 0, stream>>>(bih, bhh, biasc);

    // px = x @ W_ih^T + (b_ih + b_hh), stored packed bf16
    gemm_bt<true><<<dim3(64, 32), 256, 0, stream>>>(x, Wih, biasc, (void*)pxp, 4096, 1024);

    lstm_rec<<<NWG, 256, 0, stream>>>(wpk, pxp, htag, lstm_out);

    // logits = lstm_out @ W_out^T + b_out  -> d_out
    gemm_bt<false><<<dim3(64, 4), 256, 0, stream>>>(lstm_out, Wout, bout, (void*)out, 512, 1024);

    // log-softmax over sequence axis (columns)
    sm_partial<<<dim3(8, 32), 256, 0, stream>>>(out, pM, pS);
    sm_combine<<<1, 512, 0, stream>>>(pM, pS, cc);
    sm_apply<<<4096, 256, 0, stream>>>(out, cc);
}

// Round 8
// 16464.862 us; speedup vs baseline: 7.6843x; 1.5400x over previous
//
#include <hip/hip_runtime.h>
#include <stdint.h>

// Problem constants
#define NT   8192   // T
#define HID  1024   // H (= I)
#define NWG  128    // persistent workgroups in recurrence

// ---------- f16 helpers (packed 2 x f16 in a uint32: lo = elem0, hi = elem1) ----------
typedef _Float16 f16x2 __attribute__((ext_vector_type(2)));
__device__ __forceinline__ uint32_t f16_bits(float a) {
    return (uint32_t)__builtin_bit_cast(uint16_t, (_Float16)a);
}
__device__ __forceinline__ float f16_lo(uint32_t w) {
    return (float)__builtin_bit_cast(_Float16, (uint16_t)(w & 0xffffu));
}
__device__ __forceinline__ float f16_hi(uint32_t w) {
    return (float)__builtin_bit_cast(_Float16, (uint16_t)(w >> 16));
}
__device__ __forceinline__ uint32_t pack_f16(float a, float b) {
    return f16_bits(a) | (f16_bits(b) << 16);
}
__device__ __forceinline__ float dot2(uint32_t a, uint32_t b, float c) {
    return __builtin_amdgcn_fdot2(__builtin_bit_cast(f16x2, a),
                                  __builtin_bit_cast(f16x2, b), c, false);
}
__device__ __forceinline__ float fast_rcp(float x) { return __builtin_amdgcn_rcpf(x); }
__device__ __forceinline__ float fast_sig(float x) { return fast_rcp(1.f + __expf(-x)); }
__device__ __forceinline__ float fast_tanh(float x) {
    return 1.f - 2.f * fast_rcp(1.f + __expf(2.f * x));
}

// ---------- prep: combined bias ----------
__global__ void prep_bias(const float* __restrict__ a, const float* __restrict__ b,
                          float* __restrict__ o) {
    int i = blockIdx.x * 256 + threadIdx.x;
    if (i < 4096) o[i] = a[i] + b[i];
}

// ---------- prep: W_hh -> packed f16, per-WG layout ----------
// Layout: wpk[w][lr][u], lr = wave*8 + gate*2 + jj  <->  row R = gate*1024 + w*8 + 2*wave + jj
// word u packs cols (2u, 2u+1)
__global__ void prep_whh(const float* __restrict__ Whh, uint32_t* __restrict__ wpk) {
    int idx = blockIdx.x * 256 + threadIdx.x;        // 0 .. 128*32*512-1
    int u    = idx & 511;
    int lr   = (idx >> 9) & 31;
    int w    = idx >> 14;
    int v    = lr >> 3;
    int gate = (lr >> 1) & 3;
    int jj   = lr & 1;
    int R = gate * 1024 + w * 8 + 2 * v + jj;
    const float* rp = Whh + (size_t)R * 1024 + 2 * u;
    wpk[idx] = pack_f16(rp[0], rp[1]);
}

// ---------- fp32 tiled GEMM: out[M][N] = A[M][K] @ B[N][K]^T + bias[N] ----------
// 128x128 tile, BK=16, 256 threads, 8x8 microtile. PACK_OUT: write packed f16 pairs.
template <bool PACK_OUT>
__launch_bounds__(256)
__global__ void gemm_bt(const float* __restrict__ A, const float* __restrict__ B,
                        const float* __restrict__ bias, void* __restrict__ outp,
                        int N, int K) {
    __shared__ float As[16 * 132];
    __shared__ float Bs[16 * 132];
    const int tid = threadIdx.x;
    const int bm = blockIdx.x, bn = blockIdx.y;
    const int tx = tid & 15, ty = tid >> 4;
    const int r = tid >> 2, cf = tid & 3;

    float acc[8][8];
#pragma unroll
    for (int i = 0; i < 8; ++i)
#pragma unroll
        for (int j = 0; j < 8; ++j) acc[i][j] = 0.f;

    const float* Ap = A + (size_t)(bm * 128 + r) * K + cf * 4;
    const float* Bp = B + (size_t)(bn * 128 + r) * K + cf * 4;

    for (int k0 = 0; k0 < K; k0 += 16) {
        float4 a0 = *(const float4*)(Ap + k0);
        float4 a1 = *(const float4*)(Ap + (size_t)64 * K + k0);
        float4 b0 = *(const float4*)(Bp + k0);
        float4 b1 = *(const float4*)(Bp + (size_t)64 * K + k0);
        __syncthreads();   // protect previous iteration's LDS reads
#pragma unroll
        for (int e = 0; e < 4; ++e) {
            As[(cf * 4 + e) * 132 + r]      = ((const float*)&a0)[e];
            As[(cf * 4 + e) * 132 + r + 64] = ((const float*)&a1)[e];
            Bs[(cf * 4 + e) * 132 + r]      = ((const float*)&b0)[e];
            Bs[(cf * 4 + e) * 132 + r + 64] = ((const float*)&b1)[e];
        }
        __syncthreads();
#pragma unroll
        for (int k = 0; k < 16; ++k) {
            const float4 av0 = *(const float4*)&As[k * 132 + ty * 8];
            const float4 av1 = *(const float4*)&As[k * 132 + ty * 8 + 4];
            const float4 bv0 = *(const float4*)&Bs[k * 132 + tx * 4];
            const float4 bv1 = *(const float4*)&Bs[k * 132 + tx * 4 + 64];
            const float a[8] = {av0.x, av0.y, av0.z, av0.w, av1.x, av1.y, av1.z, av1.w};
            const float b[8] = {bv0.x, bv0.y, bv0.z, bv0.w, bv1.x, bv1.y, bv1.z, bv1.w};
#pragma unroll
            for (int i = 0; i < 8; ++i)
#pragma unroll
                for (int j = 0; j < 8; ++j) acc[i][j] = fmaf(a[i], b[j], acc[i][j]);
        }
    }

    const int mb = bm * 128 + ty * 8;
    const int n0 = bn * 128 + tx * 4, n1 = n0 + 64;
    float bb[8];
#pragma unroll
    for (int j = 0; j < 4; ++j) { bb[j] = bias[n0 + j]; bb[4 + j] = bias[n1 + j]; }

    if (PACK_OUT) {
        uint32_t* o = (uint32_t*)outp;
        const int halfN = N >> 1;
#pragma unroll
        for (int i = 0; i < 8; ++i) {
            uint2 w0, w1;
            w0.x = pack_f16(acc[i][0] + bb[0], acc[i][1] + bb[1]);
            w0.y = pack_f16(acc[i][2] + bb[2], acc[i][3] + bb[3]);
            w1.x = pack_f16(acc[i][4] + bb[4], acc[i][5] + bb[5]);
            w1.y = pack_f16(acc[i][6] + bb[6], acc[i][7] + bb[7]);
            *(uint2*)(o + (size_t)(mb + i) * halfN + (n0 >> 1)) = w0;
            *(uint2*)(o + (size_t)(mb + i) * halfN + (n1 >> 1)) = w1;
        }
    } else {
        float* o = (float*)outp;
#pragma unroll
        for (int i = 0; i < 8; ++i) {
            float4 v0, v1;
            v0.x = acc[i][0] + bb[0]; v0.y = acc[i][1] + bb[1];
            v0.z = acc[i][2] + bb[2]; v0.w = acc[i][3] + bb[3];
            v1.x = acc[i][4] + bb[4]; v1.y = acc[i][5] + bb[5];
            v1.z = acc[i][6] + bb[6]; v1.w = acc[i][7] + bb[7];
            *(float4*)(o + (size_t)(mb + i) * N + n0) = v0;
            *(float4*)(o + (size_t)(mb + i) * N + n1) = v1;
        }
    }
}

// ---------- persistent LSTM recurrence, barrier-free tagged dataflow ----------
// h word j = (tag<<16) | f16(h_j). H[s] lives in buf[s&1], tagged s. H[0]=tag 0=memset 0.
// Writer of H[s] observed all tags s-1 => every wave finished reading H[s-2] => safe to
// overwrite buf[s&1]. No barriers, no fences, no intra-WG sync in loop.
// 128 WGs x 256 threads; WG w owns units 8w..8w+7; wave v owns units 8w+2v, 8w+2v+1.
// Weights in VGPRs (64 u32/lane, statically indexed). Poll has per-lane done-skip:
// validated lanes stop issuing loads, cutting redundant same-line reads at the MALL.
__launch_bounds__(256)
__global__ void lstm_rec(const uint32_t* __restrict__ wpk, const uint32_t* __restrict__ pxp,
                         uint32_t* htag, float* __restrict__ lstm_out) {
    const int tid = threadIdx.x, w = blockIdx.x;
    const int wave = tid >> 6, L = tid & 63;

    // stage this wave's weight slice into VGPRs (coalesced; static indexing -> registers)
    uint32_t wreg[8][8];
    {
        const uint32_t* wb = wpk + (size_t)w * 16384 + (size_t)(wave * 8) * 512 + L;
#pragma unroll
        for (int rr = 0; rr < 8; ++rr)
#pragma unroll
            for (int m = 0; m < 8; ++m)
                wreg[rr][m] = wb[rr * 512 + m * 64];
    }

    float c0 = 0.f;                    // cell state, live only in lanes 0,1 of each wave
    uint64_t* buf0 = (uint64_t*)htag;          // 512 u64 = words 0..1023   (H[even])
    uint64_t* buf1 = (uint64_t*)(htag + 1024); //                           (H[odd])

    for (int t = 0; t < NT; ++t) {
        const uint32_t tg = (uint32_t)t;            // tag of H[t]
        uint64_t* srcb = (t & 1) ? buf1 : buf0;     // H[t]
        uint32_t* dstb = (uint32_t*)((t & 1) ? buf0 : buf1);  // H[t+1]
        const uint64_t tagpat = ((uint64_t)tg << 16) | ((uint64_t)tg << 48);

        // px for my gates — plain cached loads, issued before the poll so the
        // latency hides under it
        float pxv[4] = {0.f, 0.f, 0.f, 0.f};
        if (L < 2) {
#pragma unroll
            for (int g = 0; g < 4; ++g) {
                int R = g * 1024 + w * 8 + 2 * wave + L;
                uint32_t pw = pxp[(size_t)t * 2048 + (R >> 1)];
                pxv[g] = (R & 1) ? f16_hi(pw) : f16_lo(pw);
            }
        }

        // poll: lane covers 8 u64 (pairs 2(L+64m), +1); done lanes stop loading
        uint64_t hp[8];
        bool mydone = false;
        int tries = 0;
        for (;;) {
            if (!mydone) {
#pragma unroll
                for (int m = 0; m < 8; ++m)
                    hp[m] = __hip_atomic_load(srcb + (L + 64 * m),
                                              __ATOMIC_RELAXED, __HIP_MEMORY_SCOPE_AGENT);
                int ok = 1;
#pragma unroll
                for (int m = 0; m < 8; ++m)
                    ok &= ((hp[m] & 0xffff0000ffff0000ull) == tagpat);
                mydone = (ok != 0);
            }
            if (__all(mydone)) break;
            if (++tries > (1 << 15)) break;   // tripwire: hang -> visible absmax failure
        }

        // hk[m] = f16 pair (h[2(L+64m)], h[2(L+64m)+1])
        uint32_t hk[8];
#pragma unroll
        for (int m = 0; m < 8; ++m)
            hk[m] = ((uint32_t)hp[m] & 0xffffu) | (((uint32_t)(hp[m] >> 32)) << 16);

        // 8 row-dots via v_dot2_f32_f16 (rows rr = gate*2 + jj)
        float acc[8];
#pragma unroll
        for (int rr = 0; rr < 8; ++rr) {
            float a = 0.f;
#pragma unroll
            for (int m = 0; m < 8; ++m) a = dot2(wreg[rr][m], hk[m], a);
            acc[rr] = a;
        }

        // folded butterfly over bits {4,2,1}: lane L ends with row (L&7) partial
#pragma unroll
        for (int bit = 4; bit >= 1; bit >>= 1) {
#pragma unroll
            for (int i = 0; i < bit; ++i) {
                float v0 = acc[i], v1 = acc[i + bit];
                float send = (L & bit) ? v0 : v1;
                float recv = __shfl_xor(send, bit, 64);
                acc[i] = ((L & bit) ? v1 : v0) + recv;
            }
        }
        float tot = acc[0];
        tot += __shfl_xor(tot, 8, 64);
        tot += __shfl_xor(tot, 16, 64);
        tot += __shfl_xor(tot, 32, 64);
        // lane jj needs rows jj, 2+jj, 4+jj, 6+jj (held at lanes of those indices)
        float r0 = __shfl(tot, (L & 1), 64);
        float r1 = __shfl(tot, (L & 1) + 2, 64);
        float r2 = __shfl(tot, (L & 1) + 4, 64);
        float r3 = __shfl(tot, (L & 1) + 6, 64);

        // elementwise gate update: lanes 0,1 of each wave (jj = L)
        if (L < 2) {
            float gi = r0 + pxv[0];
            float gf = r1 + pxv[1];
            float gg = r2 + pxv[2];
            float go = r3 + pxv[3];
            float iv = fast_sig(gi);
            float fv = fast_sig(gf);
            float gv = fast_tanh(gg);
            float ov = fast_sig(go);
            c0 = fv * c0 + iv * gv;
            float h = ov * fast_tanh(c0);
            int j = w * 8 + 2 * wave + L;
            // publish tagged h FIRST (critical path), then the log
            uint32_t word = f16_bits(h) | ((uint32_t)(t + 1) << 16);
            __hip_atomic_store(dstb + j, word, __ATOMIC_RELAXED, __HIP_MEMORY_SCOPE_AGENT);
            lstm_out[(size_t)t * 1024 + j] = h;
        }
    }
}

// ---------- log-softmax over axis 0 (columns of [8192][512]) ----------
__global__ void sm_partial(const float* __restrict__ logits, float* __restrict__ pM,
                           float* __restrict__ pS) {
    const int cb = blockIdx.x, rb = blockIdx.y, tid = threadIdx.x;
    const int c = cb * 64 + (tid & 63);
    const int r0 = rb * 256 + (tid >> 6) * 64;
    const float* p = logits + (size_t)r0 * 512 + c;
    float m = -1e30f;
    for (int k = 0; k < 64; ++k) m = fmaxf(m, p[(size_t)k * 512]);
    float s = 0.f;
    for (int k = 0; k < 64; ++k) s += __expf(p[(size_t)k * 512] - m);
    __shared__ float sM[4][64], sS[4][64];
    sM[tid >> 6][tid & 63] = m;
    sS[tid >> 6][tid & 63] = s;
    __syncthreads();
    if (tid < 64) {
        float M = sM[0][tid];
        for (int i = 1; i < 4; ++i) M = fmaxf(M, sM[i][tid]);
        float S = 0.f;
        for (int i = 0; i < 4; ++i) S += sS[i][tid] * __expf(sM[i][tid] - M);
        pM[rb * 512 + cb * 64 + tid] = M;
        pS[rb * 512 + cb * 64 + tid] = S;
    }
}

__global__ void sm_combine(const float* __restrict__ pM, const float* __restrict__ pS,
                           float* __restrict__ cc) {
    const int c = threadIdx.x;   // 512 threads
    float M = -1e30f;
    for (int i = 0; i < 32; ++i) M = fmaxf(M, pM[i * 512 + c]);
    float S = 0.f;
    for (int i = 0; i < 32; ++i) S += pS[i * 512 + c] * __expf(pM[i * 512 + c] - M);
    cc[c] = M + logf(S);
}

__global__ void sm_apply(float* __restrict__ out, const float* __restrict__ cc) {
    const int idx = blockIdx.x * 256 + threadIdx.x;    // float4 index, exactly 1M
    float4 v = ((const float4*)out)[idx];
    float4 b = ((const float4*)cc)[idx & 127];
    v.x -= b.x; v.y -= b.y; v.z -= b.z; v.w -= b.w;
    ((float4*)out)[idx] = v;
}

// ---------- launch ----------
extern "C" void kernel_launch(void* const* d_in, const int* in_sizes, int n_in,
                              void* d_out, int out_size, void* d_ws, size_t ws_size,
                              hipStream_t stream) {
    (void)in_sizes; (void)n_in; (void)out_size; (void)ws_size;
    const float* x    = (const float*)d_in[0];
    const float* Wih  = (const float*)d_in[1];
    const float* Whh  = (const float*)d_in[2];
    const float* bih  = (const float*)d_in[3];
    const float* bhh  = (const float*)d_in[4];
    const float* Wout = (const float*)d_in[5];
    const float* bout = (const float*)d_in[6];
    float* out = (float*)d_out;

    char* ws = (char*)d_ws;
    uint32_t* pxp   = (uint32_t*)(ws + 0ull);            // 8192*2048 words   (67,108,864 B)
    uint32_t* wpk   = (uint32_t*)(ws + 67108864ull);     // 128*32*512 words  ( 8,388,608 B)
    float* lstm_out = (float*)   (ws + 75497472ull);     // 8192*1024 f32     (33,554,432 B)
    float* biasc    = (float*)   (ws + 109051904ull);    // 4096 f32 (16 KB)
    uint32_t* htag  = (uint32_t*)(ws + 109068288ull);    // 2*1024 words (8 KB)
    float* pM       = (float*)   (ws + 109076480ull);    // 32*512 f32 (64 KB)
    float* pS       = (float*)   (ws + 109142016ull);    // 32*512 f32 (64 KB)
    float* cc       = (float*)   (ws + 109207552ull);    // 512 f32

    // deterministic per-call state: H[0] = 0 with tag 0
    hipMemsetAsync(htag, 0, 8192, stream);

    prep_whh<<<8192, 256, 0, stream>>>(Whh, wpk);
    prep_bias<<<16, 256, 0, stream>>>(bih, bhh, biasc);

    // px = x @ W_ih^T + (b_ih + b_hh), stored packed f16
    gemm_bt<true><<<dim3(64, 32), 256, 0, stream>>>(x, Wih, biasc, (void*)pxp, 4096, 1024);

    lstm_rec<<<NWG, 256, 0, stream>>>(wpk, pxp, htag, lstm_out);

    // logits = lstm_out @ W_out^T + b_out  -> d_out
    gemm_bt<false><<<dim3(64, 4), 256, 0, stream>>>(lstm_out, Wout, bout, (void*)out, 512, 1024);

    // log-softmax over sequence axis (columns)
    sm_partial<<<dim3(8, 32), 256, 0, stream>>>(out, pM, pS);
    sm_combine<<<1, 512, 0, stream>>>(pM, pS, cc);
    sm_apply<<<4096, 256, 0, stream>>>(out, cc);
}